// Round 8
// baseline (349.423 us; speedup 1.0000x reference)
//
#include <hip/hip_runtime.h>
#include <hip/hip_bf16.h>
#include <stdint.h>

#define EPSF 1e-8f

typedef __attribute__((ext_vector_type(8))) short short8;
typedef __attribute__((ext_vector_type(8))) _Float16 half8;
typedef __attribute__((ext_vector_type(4))) float floatx4;

__device__ __forceinline__ unsigned short f2h(float f) {
    _Float16 h = (_Float16)f;
    return __builtin_bit_cast(unsigned short, h);
}

// ---------------- fused conversion kernel ----------------
// x -> fp16, W_in -> fp16, W_out -> fp16

__global__ void prep_kernel(const float* __restrict__ x, unsigned short* __restrict__ x16,
                            const float* __restrict__ wi, unsigned short* __restrict__ wi16,
                            const float* __restrict__ wo, unsigned short* __restrict__ wo16,
                            int nx, int nw, int nwo) {
    int i = blockIdx.x * blockDim.x + threadIdx.x;
    if (i < nx) {
        x16[i] = f2h(x[i]);
    } else if (i < nx + nw) {
        int j = i - nx;
        wi16[j] = f2h(wi[j]);
    } else if (i < nx + nw + nwo) {
        int j = i - nx - nw;
        wo16[j] = f2h(wo[j]);
    }
}

// ---------------- MFMA GEMM (C = A * B^T + bias), fp16 ----------------
// XOR-swizzled LDS (conflict-free, verified r6: SQ_LDS_BANK_CONFLICT = 0).
// XCD-aware 1-D grid decode: assuming round-robin dispatch, XCD (lin&7) owns
// GROUP consecutive n-tiles -> its B working set stays L2-resident, A-stripes
// are swept in lockstep across XCDs and served once from HBM via L3.
// Grid must be 8*GROUP n-tiles by (grid/(8*GROUP)) m-tiles, launched 1-D.

__device__ __forceinline__ void gld16(const unsigned short* g, unsigned short* l) {
    __builtin_amdgcn_global_load_lds(
        (const __attribute__((address_space(1))) unsigned int*)g,
        (__attribute__((address_space(3))) unsigned int*)l, 16, 0, 0);
}

template <int BM, int BN, int BK, int GROUP>
__global__ __launch_bounds__(256)
void gemm_bt(const unsigned short* __restrict__ Am, const unsigned short* __restrict__ Bm,
             const float* __restrict__ bias, float* __restrict__ C,
             int M, int N, int K) {
    constexpr int IF  = BM / 32;       // row fragments per wave (waves 2x2)
    constexpr int JF  = BN / 32;       // col fragments per wave
    constexpr int KH  = BK / 32;       // mfma k-steps per tile
    constexpr int CPR = BK / 8;        // 16B chunks per row
    extern __shared__ unsigned short smem[];
    unsigned short* sA = smem;
    unsigned short* sB = smem + BM * BK;

    const int tid  = threadIdx.x;
    const int lane = tid & 63;
    const int wid  = tid >> 6;
    const int wr   = wid >> 1, wc = wid & 1;
    const int m16  = lane & 15, quad = lane >> 4;

    // XCD-locality decode
    const int lin = blockIdx.x;
    const int nt  = (lin & 7) * GROUP + ((lin >> 3) % GROUP);
    const int mt  = (lin >> 3) / GROUP;
    const int rowA0 = mt * BM;
    const int rowB0 = nt * BN;

    floatx4 acc[IF][JF];
#pragma unroll
    for (int i = 0; i < IF; i++)
#pragma unroll
        for (int j = 0; j < JF; j++) acc[i][j] = (floatx4){0.f, 0.f, 0.f, 0.f};

    const int nk = K / BK;
    for (int kt = 0; kt < nk; ++kt) {
        const int k0 = kt * BK;
#pragma unroll
        for (int i = 0; i < BM * CPR / 256; i++) {
            int c = tid + 256 * i;
            int r = c / CPR, ccl = c % CPR;
            int ccg = ccl ^ (r & (CPR - 1));   // swizzled source chunk
            gld16(Am + (size_t)(rowA0 + r) * K + k0 + ccg * 8, sA + c * 8);
        }
#pragma unroll
        for (int i = 0; i < BN * CPR / 256; i++) {
            int c = tid + 256 * i;
            int r = c / CPR, ccl = c % CPR;
            int ccg = ccl ^ (r & (CPR - 1));
            gld16(Bm + (size_t)(rowB0 + r) * K + k0 + ccg * 8, sB + c * 8);
        }
        __syncthreads();

#pragma unroll
        for (int kh = 0; kh < KH; kh++) {
            short8 a[IF], b[JF];
            const int kc = kh * 4 + quad;
#pragma unroll
            for (int i = 0; i < IF; i++) {
                int ra = wr * (BM / 2) + i * 16 + m16;
                int pa = ra * CPR + (kc ^ (ra & (CPR - 1)));
                a[i] = *(const short8*)(sA + pa * 8);
            }
#pragma unroll
            for (int j = 0; j < JF; j++) {
                int rb = wc * (BN / 2) + j * 16 + m16;
                int pb = rb * CPR + (kc ^ (rb & (CPR - 1)));
                b[j] = *(const short8*)(sB + pb * 8);
            }
#pragma unroll
            for (int i = 0; i < IF; i++)
#pragma unroll
                for (int j = 0; j < JF; j++)
                    acc[i][j] = __builtin_amdgcn_mfma_f32_16x16x32_f16(
                        __builtin_bit_cast(half8, a[i]), __builtin_bit_cast(half8, b[j]),
                        acc[i][j], 0, 0, 0);
        }
        __syncthreads();
    }

    // C/D layout: col=lane&15, row=quad*4+reg (verified m89/m91)
#pragma unroll
    for (int i = 0; i < IF; i++) {
#pragma unroll
        for (int j = 0; j < JF; j++) {
            int col  = rowB0 + wc * (BN / 2) + j * 16 + m16;
            float bv = bias[col];
#pragma unroll
            for (int r = 0; r < 4; r++) {
                int row = rowA0 + wr * (BM / 2) + i * 16 + quad * 4 + r;
                C[(size_t)row * N + col] = acc[i][j][r] + bv;
            }
        }
    }
}

// ---------------- hierarchical quaternion prefix-product scan ----------------

struct Q { float w, x, y, z; };

__device__ __forceinline__ Q qmul(Q a, Q b) {   // a later (left), b earlier
    Q r;
    r.w = a.w * b.w - a.x * b.x - a.y * b.y - a.z * b.z;
    r.x = a.w * b.x + a.x * b.w + a.y * b.z - a.z * b.y;
    r.y = a.w * b.y - a.x * b.z + a.y * b.w + a.z * b.x;
    r.z = a.w * b.z + a.x * b.y - a.y * b.x + a.z * b.w;
    return r;
}
__device__ __forceinline__ Q qnorm(Q a) {
    float nn = a.w * a.w + a.x * a.x + a.y * a.y + a.z * a.z;
    float inv = __frsqrt_rn(nn);
    Q r; r.w = a.w * inv; r.x = a.x * inv; r.y = a.y * inv; r.z = a.z * inv;
    return r;
}
__device__ __forceinline__ Q vquat(float vx, float vy, float vz) {
    float th = sqrtf(vx * vx + vy * vy + vz * vz);
    float s_, c_;
    __sincosf(th, &s_, &c_);
    float k = __fdividef(s_, th + EPSF);
    Q q; q.w = c_; q.x = k * vx; q.y = k * vy; q.z = k * vz;
    return q;
}

#define SEG  64
#define NSEG 32

// block: 256 thr = 64 h x 4 segments; grid (NSEG/4, H/64, B)
__global__ __launch_bounds__(256)
void seg_prod_kernel(const float* __restrict__ v, float* __restrict__ partials,
                     int S, int H) {
    const int b  = blockIdx.z;
    const int h  = blockIdx.y * 64 + (threadIdx.x & 63);
    const int sg = blockIdx.x * 4 + (threadIdx.x >> 6);
    const int s0 = sg * SEG;
    const size_t vstep = (size_t)3 * H;
    const float* vp = v + ((size_t)b * S + s0) * vstep + (size_t)h * 3;

    constexpr int CH = 8;
    float ax[CH], ay[CH], az[CH], bx[CH], by[CH], bz[CH];
#pragma unroll
    for (int i = 0; i < CH; ++i) {
        ax[i] = vp[i * vstep + 0]; ay[i] = vp[i * vstep + 1]; az[i] = vp[i * vstep + 2];
    }
    Q c = {1.f, 0.f, 0.f, 0.f};
    const int NC = SEG / CH;  // 8 chunks
    for (int cc = 0; cc < NC; cc += 2) {
        if (cc + 1 < NC) {
            const float* p = vp + (size_t)(cc + 1) * CH * vstep;
#pragma unroll
            for (int i = 0; i < CH; ++i) {
                bx[i] = p[i * vstep + 0]; by[i] = p[i * vstep + 1]; bz[i] = p[i * vstep + 2];
            }
        }
#pragma unroll
        for (int i = 0; i < CH; ++i) c = qmul(vquat(ax[i], ay[i], az[i]), c);
        if (cc + 2 < NC) {
            const float* p = vp + (size_t)(cc + 2) * CH * vstep;
#pragma unroll
            for (int i = 0; i < CH; ++i) {
                ax[i] = p[i * vstep + 0]; ay[i] = p[i * vstep + 1]; az[i] = p[i * vstep + 2];
            }
        }
#pragma unroll
        for (int i = 0; i < CH; ++i) c = qmul(vquat(bx[i], by[i], bz[i]), c);
    }
    float4* dst = (float4*)(partials + (((size_t)b * NSEG + sg) * H + h) * 4);
    *dst = make_float4(c.w, c.x, c.y, c.z);
}

// 4096 threads, one per chain; batch-load all segments, exclusive scan.
__global__ __launch_bounds__(256)
void seg_scan_kernel(float* __restrict__ partials, float* __restrict__ m_final, int H) {
    const int t = blockIdx.x * blockDim.x + threadIdx.x;  // b*H + h
    const int b = t >> 10, h = t & 1023;
    float4 sv[NSEG];
#pragma unroll
    for (int sg = 0; sg < NSEG; ++sg)
        sv[sg] = *(const float4*)(partials + (((size_t)b * NSEG + sg) * H + h) * 4);
    Q r = {1.f, 0.f, 0.f, 0.f};
#pragma unroll
    for (int sg = 0; sg < NSEG; ++sg) {
        *(float4*)(partials + (((size_t)b * NSEG + sg) * H + h) * 4) =
            make_float4(r.w, r.x, r.y, r.z);   // exclusive prefix
        Q pq = {sv[sg].x, sv[sg].y, sv[sg].z, sv[sg].w};
        r = qmul(pq, r);
    }
    r = qnorm(r);
    float* mf = m_final + (size_t)t * 4;
    mf[0] = r.w; mf[1] = r.x; mf[2] = r.y; mf[3] = r.z;
}

// same mapping as seg_prod; applies prefix, writes fp16 states coalesced.
__global__ __launch_bounds__(256)
void apply_kernel(const float* __restrict__ v, const float* __restrict__ pfx,
                  unsigned short* __restrict__ st, int S, int H) {
    const int b  = blockIdx.z;
    const int h  = blockIdx.y * 64 + (threadIdx.x & 63);
    const int sg = blockIdx.x * 4 + (threadIdx.x >> 6);
    const int s0 = sg * SEG;
    const size_t vstep = (size_t)3 * H;
    const size_t sstep = (size_t)4 * H;
    const float* vp = v + ((size_t)b * S + s0) * vstep + (size_t)h * 3;
    unsigned short* sp = st + ((size_t)b * S + s0) * sstep + (size_t)h * 4;

    float4 p = *(const float4*)(pfx + (((size_t)b * NSEG + sg) * H + h) * 4);
    Q R = {p.x, p.y, p.z, p.w};

    constexpr int CH = 8;
    float ax[CH], ay[CH], az[CH], bx[CH], by[CH], bz[CH];
#pragma unroll
    for (int i = 0; i < CH; ++i) {
        ax[i] = vp[i * vstep + 0]; ay[i] = vp[i * vstep + 1]; az[i] = vp[i * vstep + 2];
    }
    const int NC = SEG / CH;
    for (int cc = 0; cc < NC; cc += 2) {
        if (cc + 1 < NC) {
            const float* pp = vp + (size_t)(cc + 1) * CH * vstep;
#pragma unroll
            for (int i = 0; i < CH; ++i) {
                bx[i] = pp[i * vstep + 0]; by[i] = pp[i * vstep + 1]; bz[i] = pp[i * vstep + 2];
            }
        }
#pragma unroll
        for (int i = 0; i < CH; ++i) {
            R = qmul(vquat(ax[i], ay[i], az[i]), R);
            Q m = qnorm(R);
            ushort4 u; u.x = f2h(m.w); u.y = f2h(m.x); u.z = f2h(m.y); u.w = f2h(m.z);
            *(ushort4*)(sp + (size_t)(cc * CH + i) * sstep) = u;
        }
        if (cc + 2 < NC) {
            const float* pp = vp + (size_t)(cc + 2) * CH * vstep;
#pragma unroll
            for (int i = 0; i < CH; ++i) {
                ax[i] = pp[i * vstep + 0]; ay[i] = pp[i * vstep + 1]; az[i] = pp[i * vstep + 2];
            }
        }
#pragma unroll
        for (int i = 0; i < CH; ++i) {
            R = qmul(vquat(bx[i], by[i], bz[i]), R);
            Q m = qnorm(R);
            ushort4 u; u.x = f2h(m.w); u.y = f2h(m.x); u.z = f2h(m.y); u.w = f2h(m.z);
            *(ushort4*)(sp + (size_t)((cc + 1) * CH + i) * sstep) = u;
        }
    }
}

// ---------------- launch ----------------

extern "C" void kernel_launch(void* const* d_in, const int* in_sizes, int n_in,
                              void* d_out, int out_size, void* d_ws, size_t ws_size,
                              hipStream_t stream) {
    const float* x     = (const float*)d_in[0];
    const float* W_in  = (const float*)d_in[1];
    const float* b_in  = (const float*)d_in[2];
    const float* W_out = (const float*)d_in[3];
    const float* b_out = (const float*)d_in[4];
    float* out = (float*)d_out;

    const int B = 4, S = 2048, D = 1024, H = 1024;
    const int M  = B * S;    // 8192
    const int N1 = 3 * H;    // 3072
    const int K1 = D;        // 1024
    const int N2 = D;        // 1024
    const int K2 = 4 * H;    // 4096

    char* ws = (char*)d_ws;
    float*          v    = (float*)(ws);                        // 96 MB
    unsigned short* st   = (unsigned short*)(ws + 100663296u);  // 64 MB (after GEMM1)
    unsigned short* x16  = (unsigned short*)(ws + 100663296u);  // consumed by GEMM1
    unsigned short* wi16 = (unsigned short*)(ws + 100663296u + 16777216u);
    unsigned short* wo16 = (unsigned short*)(ws + 167772160u);  // 8 MB, lives to GEMM2

    // partials (2 MB) live in d_out — free until GEMM2 overwrites it last.
    float* partials = out;

    const int nx  = M * K1;    // 8388608
    const int nw  = N1 * K1;   // 3145728
    const int nwo = N2 * K2;   // 4194304
    const int ntot = nx + nw + nwo;

    prep_kernel<<<(ntot + 255) / 256, 256, 0, stream>>>(
        x, x16, W_in, wi16, W_out, wo16, nx, nw, nwo);

    // v = x @ W_in^T + b_in   (fp16, BK=64 swizzled; 24 n-tiles = 8 XCD x 3)
    gemm_bt<128, 128, 64, 3><<<(N1 / 128) * (M / 128), 256, 32768, stream>>>(
        x16, wi16, b_in, v, M, N1, K1);

    // hierarchical scan
    dim3 sg_grid(NSEG / 4, H / 64, B);
    seg_prod_kernel<<<sg_grid, 256, 0, stream>>>(v, partials, S, H);
    seg_scan_kernel<<<(B * H) / 256, 256, 0, stream>>>(partials, out + (size_t)M * D, H);
    apply_kernel<<<sg_grid, 256, 0, stream>>>(v, partials, st, S, H);

    // out = states @ W_out^T + b_out  (fp16; 8 n-tiles = 8 XCD x 1)
    gemm_bt<128, 128, 64, 1><<<(N2 / 128) * (M / 128), 256, 32768, stream>>>(
        st, wo16, b_out, out, M, N2, K2);
}

// Round 9
// 348.560 us; speedup vs baseline: 1.0025x; 1.0025x over previous
//
#include <hip/hip_runtime.h>
#include <hip/hip_bf16.h>
#include <stdint.h>

#define EPSF 1e-8f

typedef __attribute__((ext_vector_type(8))) short short8;
typedef __attribute__((ext_vector_type(8))) _Float16 half8;
typedef __attribute__((ext_vector_type(4))) float floatx4;

__device__ __forceinline__ unsigned short f2h(float f) {
    _Float16 h = (_Float16)f;
    return __builtin_bit_cast(unsigned short, h);
}

// ---------------- fused conversion kernel (float4-vectorized) ----------------

__global__ void prep_kernel(const float4* __restrict__ x4, ushort4* __restrict__ x16,
                            const float4* __restrict__ wi4, ushort4* __restrict__ wi16,
                            const float4* __restrict__ wo4, ushort4* __restrict__ wo16,
                            int nx4, int nw4, int nwo4) {
    int i = blockIdx.x * blockDim.x + threadIdx.x;
    float4 f; ushort4 u;
    if (i < nx4) {
        f = x4[i];
        u.x = f2h(f.x); u.y = f2h(f.y); u.z = f2h(f.z); u.w = f2h(f.w);
        x16[i] = u;
    } else if (i < nx4 + nw4) {
        int j = i - nx4;
        f = wi4[j];
        u.x = f2h(f.x); u.y = f2h(f.y); u.z = f2h(f.z); u.w = f2h(f.w);
        wi16[j] = u;
    } else if (i < nx4 + nw4 + nwo4) {
        int j = i - nx4 - nw4;
        f = wo4[j];
        u.x = f2h(f.x); u.y = f2h(f.y); u.z = f2h(f.z); u.w = f2h(f.w);
        wo16[j] = u;
    }
}

// ---------------- MFMA GEMM (C = A * B^T + bias), fp16 ----------------
// XOR-swizzled LDS (conflict-free, verified r6: SQ_LDS_BANK_CONFLICT = 0).
// Plain 2D grid (r6/r7/r8 A/B: block ordering does not move FETCH_SIZE).

__device__ __forceinline__ void gld16(const unsigned short* g, unsigned short* l) {
    __builtin_amdgcn_global_load_lds(
        (const __attribute__((address_space(1))) unsigned int*)g,
        (__attribute__((address_space(3))) unsigned int*)l, 16, 0, 0);
}

template <int BM, int BN, int BK>
__global__ __launch_bounds__(256)
void gemm_bt(const unsigned short* __restrict__ Am, const unsigned short* __restrict__ Bm,
             const float* __restrict__ bias, float* __restrict__ C,
             int M, int N, int K) {
    constexpr int IF  = BM / 32;       // row fragments per wave (waves 2x2)
    constexpr int JF  = BN / 32;       // col fragments per wave
    constexpr int KH  = BK / 32;       // mfma k-steps per tile
    constexpr int CPR = BK / 8;        // 16B chunks per row
    extern __shared__ unsigned short smem[];
    unsigned short* sA = smem;
    unsigned short* sB = smem + BM * BK;

    const int tid  = threadIdx.x;
    const int lane = tid & 63;
    const int wid  = tid >> 6;
    const int wr   = wid >> 1, wc = wid & 1;
    const int m16  = lane & 15, quad = lane >> 4;

    const int rowA0 = blockIdx.y * BM;
    const int rowB0 = blockIdx.x * BN;

    floatx4 acc[IF][JF];
#pragma unroll
    for (int i = 0; i < IF; i++)
#pragma unroll
        for (int j = 0; j < JF; j++) acc[i][j] = (floatx4){0.f, 0.f, 0.f, 0.f};

    const int nk = K / BK;
    for (int kt = 0; kt < nk; ++kt) {
        const int k0 = kt * BK;
#pragma unroll
        for (int i = 0; i < BM * CPR / 256; i++) {
            int c = tid + 256 * i;
            int r = c / CPR, ccl = c % CPR;
            int ccg = ccl ^ (r & (CPR - 1));   // swizzled source chunk
            gld16(Am + (size_t)(rowA0 + r) * K + k0 + ccg * 8, sA + c * 8);
        }
#pragma unroll
        for (int i = 0; i < BN * CPR / 256; i++) {
            int c = tid + 256 * i;
            int r = c / CPR, ccl = c % CPR;
            int ccg = ccl ^ (r & (CPR - 1));
            gld16(Bm + (size_t)(rowB0 + r) * K + k0 + ccg * 8, sB + c * 8);
        }
        __syncthreads();

#pragma unroll
        for (int kh = 0; kh < KH; kh++) {
            const int kc = kh * 4 + quad;
            short8 b[JF];
#pragma unroll
            for (int j = 0; j < JF; j++) {
                int rb = wc * (BN / 2) + j * 16 + m16;
                int pb = rb * CPR + (kc ^ (rb & (CPR - 1)));
                b[j] = *(const short8*)(sB + pb * 8);
            }
#pragma unroll
            for (int i = 0; i < IF; i++) {
                int ra = wr * (BM / 2) + i * 16 + m16;
                int pa = ra * CPR + (kc ^ (ra & (CPR - 1)));
                short8 a = *(const short8*)(sA + pa * 8);
#pragma unroll
                for (int j = 0; j < JF; j++)
                    acc[i][j] = __builtin_amdgcn_mfma_f32_16x16x32_f16(
                        __builtin_bit_cast(half8, a), __builtin_bit_cast(half8, b[j]),
                        acc[i][j], 0, 0, 0);
            }
        }
        __syncthreads();
    }

    // C/D layout: col=lane&15, row=quad*4+reg (verified m89/m91)
#pragma unroll
    for (int i = 0; i < IF; i++) {
#pragma unroll
        for (int j = 0; j < JF; j++) {
            int col  = rowB0 + wc * (BN / 2) + j * 16 + m16;
            float bv = bias[col];
#pragma unroll
            for (int r = 0; r < 4; r++) {
                int row = rowA0 + wr * (BM / 2) + i * 16 + quad * 4 + r;
                C[(size_t)row * N + col] = acc[i][j][r] + bv;
            }
        }
    }
}

// ---------------- hierarchical quaternion prefix-product scan ----------------

struct Q { float w, x, y, z; };

__device__ __forceinline__ Q qmul(Q a, Q b) {   // a later (left), b earlier
    Q r;
    r.w = a.w * b.w - a.x * b.x - a.y * b.y - a.z * b.z;
    r.x = a.w * b.x + a.x * b.w + a.y * b.z - a.z * b.y;
    r.y = a.w * b.y - a.x * b.z + a.y * b.w + a.z * b.x;
    r.z = a.w * b.z + a.x * b.y - a.y * b.x + a.z * b.w;
    return r;
}
__device__ __forceinline__ Q qnorm(Q a) {
    float nn = a.w * a.w + a.x * a.x + a.y * a.y + a.z * a.z;
    float inv = __frsqrt_rn(nn);
    Q r; r.w = a.w * inv; r.x = a.x * inv; r.y = a.y * inv; r.z = a.z * inv;
    return r;
}
__device__ __forceinline__ Q vquat(float vx, float vy, float vz) {
    float th = sqrtf(vx * vx + vy * vy + vz * vz);
    float s_, c_;
    __sincosf(th, &s_, &c_);
    float k = __fdividef(s_, th + EPSF);
    Q q; q.w = c_; q.x = k * vx; q.y = k * vy; q.z = k * vz;
    return q;
}

#define SEG  64
#define NSEG 32

// block: 256 thr = 64 h x 4 segments; grid (NSEG/4, H/64, B)
__global__ __launch_bounds__(256)
void seg_prod_kernel(const float* __restrict__ v, float* __restrict__ partials,
                     int S, int H) {
    const int b  = blockIdx.z;
    const int h  = blockIdx.y * 64 + (threadIdx.x & 63);
    const int sg = blockIdx.x * 4 + (threadIdx.x >> 6);
    const int s0 = sg * SEG;
    const size_t vstep = (size_t)3 * H;
    const float* vp = v + ((size_t)b * S + s0) * vstep + (size_t)h * 3;

    constexpr int CH = 8;
    float ax[CH], ay[CH], az[CH], bx[CH], by[CH], bz[CH];
#pragma unroll
    for (int i = 0; i < CH; ++i) {
        ax[i] = vp[i * vstep + 0]; ay[i] = vp[i * vstep + 1]; az[i] = vp[i * vstep + 2];
    }
    Q c = {1.f, 0.f, 0.f, 0.f};
    const int NC = SEG / CH;  // 8 chunks
    for (int cc = 0; cc < NC; cc += 2) {
        if (cc + 1 < NC) {
            const float* p = vp + (size_t)(cc + 1) * CH * vstep;
#pragma unroll
            for (int i = 0; i < CH; ++i) {
                bx[i] = p[i * vstep + 0]; by[i] = p[i * vstep + 1]; bz[i] = p[i * vstep + 2];
            }
        }
#pragma unroll
        for (int i = 0; i < CH; ++i) c = qmul(vquat(ax[i], ay[i], az[i]), c);
        if (cc + 2 < NC) {
            const float* p = vp + (size_t)(cc + 2) * CH * vstep;
#pragma unroll
            for (int i = 0; i < CH; ++i) {
                ax[i] = p[i * vstep + 0]; ay[i] = p[i * vstep + 1]; az[i] = p[i * vstep + 2];
            }
        }
#pragma unroll
        for (int i = 0; i < CH; ++i) c = qmul(vquat(bx[i], by[i], bz[i]), c);
    }
    float4* dst = (float4*)(partials + (((size_t)b * NSEG + sg) * H + h) * 4);
    *dst = make_float4(c.w, c.x, c.y, c.z);
}

// fused scan+apply: each block loads ALL segment partials for its 64 h into
// LDS, computes its 4 segments' exclusive prefixes locally (32 qmuls max),
// applies them to re-derived quats, writes fp16 states; sg==NSEG-1 threads
// also emit m_final. (replaces the separate seg_scan kernel + round trip)
__global__ __launch_bounds__(256)
void apply_kernel(const float* __restrict__ v, const float* __restrict__ partials,
                  unsigned short* __restrict__ st, float* __restrict__ m_final,
                  int S, int H) {
    const int b   = blockIdx.z;
    const int hb  = blockIdx.y * 64;
    const int hl  = threadIdx.x & 63;
    const int h   = hb + hl;
    const int sg  = blockIdx.x * 4 + (threadIdx.x >> 6);
    const int s0  = sg * SEG;
    const size_t vstep = (size_t)3 * H;
    const size_t sstep = (size_t)4 * H;
    const float* vp = v + ((size_t)b * S + s0) * vstep + (size_t)h * 3;
    unsigned short* sp = st + ((size_t)b * S + s0) * sstep + (size_t)h * 4;

    __shared__ float4 lp[NSEG][64];
    for (int i = threadIdx.x; i < NSEG * 64; i += 256) {
        int s2 = i >> 6, hh = i & 63;
        lp[s2][hh] = *(const float4*)(partials + (((size_t)b * NSEG + s2) * H + hb + hh) * 4);
    }
    __syncthreads();

    Q R = {1.f, 0.f, 0.f, 0.f};
    for (int s2 = 0; s2 < sg; ++s2) {           // wave-uniform trip count
        float4 pv = lp[s2][hl];
        Q pq = {pv.x, pv.y, pv.z, pv.w};
        R = qmul(pq, R);
    }

    constexpr int CH = 8;
    float ax[CH], ay[CH], az[CH], bx[CH], by[CH], bz[CH];
#pragma unroll
    for (int i = 0; i < CH; ++i) {
        ax[i] = vp[i * vstep + 0]; ay[i] = vp[i * vstep + 1]; az[i] = vp[i * vstep + 2];
    }
    const int NC = SEG / CH;
    for (int cc = 0; cc < NC; cc += 2) {
        if (cc + 1 < NC) {
            const float* pp = vp + (size_t)(cc + 1) * CH * vstep;
#pragma unroll
            for (int i = 0; i < CH; ++i) {
                bx[i] = pp[i * vstep + 0]; by[i] = pp[i * vstep + 1]; bz[i] = pp[i * vstep + 2];
            }
        }
#pragma unroll
        for (int i = 0; i < CH; ++i) {
            R = qmul(vquat(ax[i], ay[i], az[i]), R);
            Q m = qnorm(R);
            ushort4 u; u.x = f2h(m.w); u.y = f2h(m.x); u.z = f2h(m.y); u.w = f2h(m.z);
            *(ushort4*)(sp + (size_t)(cc * CH + i) * sstep) = u;
        }
        if (cc + 2 < NC) {
            const float* pp = vp + (size_t)(cc + 2) * CH * vstep;
#pragma unroll
            for (int i = 0; i < CH; ++i) {
                ax[i] = pp[i * vstep + 0]; ay[i] = pp[i * vstep + 1]; az[i] = pp[i * vstep + 2];
            }
        }
#pragma unroll
        for (int i = 0; i < CH; ++i) {
            R = qmul(vquat(bx[i], by[i], bz[i]), R);
            Q m = qnorm(R);
            ushort4 u; u.x = f2h(m.w); u.y = f2h(m.x); u.z = f2h(m.y); u.w = f2h(m.z);
            *(ushort4*)(sp + (size_t)((cc + 1) * CH + i) * sstep) = u;
        }
    }

    if (sg == NSEG - 1) {
        Q m = qnorm(R);     // inclusive product of whole chain
        float* mf = m_final + ((size_t)b * H + h) * 4;
        mf[0] = m.w; mf[1] = m.x; mf[2] = m.y; mf[3] = m.z;
    }
}

// ---------------- launch ----------------

extern "C" void kernel_launch(void* const* d_in, const int* in_sizes, int n_in,
                              void* d_out, int out_size, void* d_ws, size_t ws_size,
                              hipStream_t stream) {
    const float* x     = (const float*)d_in[0];
    const float* W_in  = (const float*)d_in[1];
    const float* b_in  = (const float*)d_in[2];
    const float* W_out = (const float*)d_in[3];
    const float* b_out = (const float*)d_in[4];
    float* out = (float*)d_out;

    const int B = 4, S = 2048, D = 1024, H = 1024;
    const int M  = B * S;    // 8192
    const int N1 = 3 * H;    // 3072
    const int K1 = D;        // 1024
    const int N2 = D;        // 1024
    const int K2 = 4 * H;    // 4096

    char* ws = (char*)d_ws;
    float*          v    = (float*)(ws);                        // 96 MB
    unsigned short* st   = (unsigned short*)(ws + 100663296u);  // 64 MB (after GEMM1)
    unsigned short* x16  = (unsigned short*)(ws + 100663296u);  // consumed by GEMM1
    unsigned short* wi16 = (unsigned short*)(ws + 100663296u + 16777216u);
    unsigned short* wo16 = (unsigned short*)(ws + 167772160u);  // 8 MB, lives to GEMM2

    // partials (2 MB) live in d_out — free until GEMM2 overwrites it last.
    float* partials = out;

    const int nx  = M * K1;    // 8388608
    const int nw  = N1 * K1;   // 3145728
    const int nwo = N2 * K2;   // 4194304
    const int n4  = (nx + nw + nwo) / 4;

    prep_kernel<<<(n4 + 255) / 256, 256, 0, stream>>>(
        (const float4*)x, (ushort4*)x16, (const float4*)W_in, (ushort4*)wi16,
        (const float4*)W_out, (ushort4*)wo16, nx / 4, nw / 4, nwo / 4);

    // v = x @ W_in^T + b_in   (fp16, 128x256 BK=64 swizzled; A-demand halved)
    gemm_bt<128, 256, 64><<<dim3(N1 / 256, M / 128), 256, 49152, stream>>>(
        x16, wi16, b_in, v, M, N1, K1);

    // hierarchical scan (2 kernels; scan fused into apply)
    dim3 sg_grid(NSEG / 4, H / 64, B);
    seg_prod_kernel<<<sg_grid, 256, 0, stream>>>(v, partials, S, H);
    apply_kernel<<<sg_grid, 256, 0, stream>>>(v, partials, st, out + (size_t)M * D, S, H);

    // out = states @ W_out^T + b_out  (fp16, 128x128 BK=64 swizzled)
    gemm_bt<128, 128, 64><<<dim3(N2 / 128, M / 128), 256, 32768, stream>>>(
        st, wo16, b_out, out, M, N2, K2);
}

// Round 10
// 325.128 us; speedup vs baseline: 1.0747x; 1.0721x over previous
//
#include <hip/hip_runtime.h>
#include <hip/hip_bf16.h>
#include <stdint.h>

#define EPSF 1e-8f

typedef __attribute__((ext_vector_type(8))) short short8;
typedef __attribute__((ext_vector_type(8))) _Float16 half8;
typedef __attribute__((ext_vector_type(16))) float floatx16;

__device__ __forceinline__ unsigned short f2h(float f) {
    _Float16 h = (_Float16)f;
    return __builtin_bit_cast(unsigned short, h);
}

// ---------------- fused conversion kernel (float4-vectorized) ----------------

__global__ void prep_kernel(const float4* __restrict__ x4, ushort4* __restrict__ x16,
                            const float4* __restrict__ wi4, ushort4* __restrict__ wi16,
                            const float4* __restrict__ wo4, ushort4* __restrict__ wo16,
                            int nx4, int nw4, int nwo4) {
    int i = blockIdx.x * blockDim.x + threadIdx.x;
    float4 f; ushort4 u;
    if (i < nx4) {
        f = x4[i];
        u.x = f2h(f.x); u.y = f2h(f.y); u.z = f2h(f.z); u.w = f2h(f.w);
        x16[i] = u;
    } else if (i < nx4 + nw4) {
        int j = i - nx4;
        f = wi4[j];
        u.x = f2h(f.x); u.y = f2h(f.y); u.z = f2h(f.z); u.w = f2h(f.w);
        wi16[j] = u;
    } else if (i < nx4 + nw4 + nwo4) {
        int j = i - nx4 - nw4;
        f = wo4[j];
        u.x = f2h(f.x); u.y = f2h(f.y); u.z = f2h(f.z); u.w = f2h(f.w);
        wo16[j] = u;
    }
}

// ---------------- MFMA GEMM (C = A * B^T + bias), fp16, 32x32x16 ----------------
// XOR-swizzled LDS staging (verified conflict-free for 16x16 reads in r6).
// 32x32x16 MFMA: half the instruction count of 16x16x32 at ~14% higher
// FLOP/cyc (m119). Fragment layouts:
//   A/B: m|n = lane&31, k = (lane>>5)*8 + i   (4 VGPRs = 8 fp16)
//   C/D: col = lane&31, row = (reg&3) + 8*(reg>>2) + 4*(lane>>5)  [m74/m101]

__device__ __forceinline__ void gld16(const unsigned short* g, unsigned short* l) {
    __builtin_amdgcn_global_load_lds(
        (const __attribute__((address_space(1))) unsigned int*)g,
        (__attribute__((address_space(3))) unsigned int*)l, 16, 0, 0);
}

template <int BM, int BN, int BK>
__global__ __launch_bounds__(256)
void gemm_bt(const unsigned short* __restrict__ Am, const unsigned short* __restrict__ Bm,
             const float* __restrict__ bias, float* __restrict__ C,
             int M, int N, int K) {
    constexpr int IF  = BM / 64;       // 32-row fragments per wave (waves 2x2)
    constexpr int JF  = BN / 64;       // 32-col fragments per wave
    constexpr int KH  = BK / 16;       // mfma k-steps per tile
    constexpr int CPR = BK / 8;        // 16B chunks per row
    extern __shared__ unsigned short smem[];
    unsigned short* sA = smem;
    unsigned short* sB = smem + BM * BK;

    const int tid  = threadIdx.x;
    const int lane = tid & 63;
    const int wid  = tid >> 6;
    const int wr   = wid >> 1, wc = wid & 1;
    const int m32  = lane & 31, half = lane >> 5;

    const int rowA0 = blockIdx.y * BM;
    const int rowB0 = blockIdx.x * BN;

    floatx16 acc[IF][JF];
#pragma unroll
    for (int i = 0; i < IF; i++)
#pragma unroll
        for (int j = 0; j < JF; j++)
#pragma unroll
            for (int r = 0; r < 16; r++) acc[i][j][r] = 0.f;

    const int nk = K / BK;
    for (int kt = 0; kt < nk; ++kt) {
        const int k0 = kt * BK;
#pragma unroll
        for (int i = 0; i < BM * CPR / 256; i++) {
            int c = tid + 256 * i;
            int r = c / CPR, ccl = c % CPR;
            int ccg = ccl ^ (r & (CPR - 1));   // swizzled source chunk
            gld16(Am + (size_t)(rowA0 + r) * K + k0 + ccg * 8, sA + c * 8);
        }
#pragma unroll
        for (int i = 0; i < BN * CPR / 256; i++) {
            int c = tid + 256 * i;
            int r = c / CPR, ccl = c % CPR;
            int ccg = ccl ^ (r & (CPR - 1));
            gld16(Bm + (size_t)(rowB0 + r) * K + k0 + ccg * 8, sB + c * 8);
        }
        __syncthreads();

#pragma unroll
        for (int kh = 0; kh < KH; kh++) {
            const int kc = kh * 2 + half;      // 16B chunk index of this lane's k
            short8 a[IF], b[JF];
#pragma unroll
            for (int i = 0; i < IF; i++) {
                int ra = wr * (BM / 2) + i * 32 + m32;
                int pa = ra * CPR + (kc ^ (ra & (CPR - 1)));
                a[i] = *(const short8*)(sA + pa * 8);
            }
#pragma unroll
            for (int j = 0; j < JF; j++) {
                int rb = wc * (BN / 2) + j * 32 + m32;
                int pb = rb * CPR + (kc ^ (rb & (CPR - 1)));
                b[j] = *(const short8*)(sB + pb * 8);
            }
#pragma unroll
            for (int i = 0; i < IF; i++)
#pragma unroll
                for (int j = 0; j < JF; j++)
                    acc[i][j] = __builtin_amdgcn_mfma_f32_32x32x16_f16(
                        __builtin_bit_cast(half8, a[i]), __builtin_bit_cast(half8, b[j]),
                        acc[i][j], 0, 0, 0);
        }
        __syncthreads();
    }

    // C/D: col=lane&31, row=(reg&3)+8*(reg>>2)+4*half  [verified m74/m101]
#pragma unroll
    for (int i = 0; i < IF; i++) {
#pragma unroll
        for (int j = 0; j < JF; j++) {
            int col  = rowB0 + wc * (BN / 2) + j * 32 + m32;
            float bv = bias[col];
#pragma unroll
            for (int r = 0; r < 16; r++) {
                int row = rowA0 + wr * (BM / 2) + i * 32 + (r & 3) + 8 * (r >> 2) + 4 * half;
                C[(size_t)row * N + col] = acc[i][j][r] + bv;
            }
        }
    }
}

// ---------------- hierarchical quaternion prefix-product scan ----------------

struct Q { float w, x, y, z; };

__device__ __forceinline__ Q qmul(Q a, Q b) {   // a later (left), b earlier
    Q r;
    r.w = a.w * b.w - a.x * b.x - a.y * b.y - a.z * b.z;
    r.x = a.w * b.x + a.x * b.w + a.y * b.z - a.z * b.y;
    r.y = a.w * b.y - a.x * b.z + a.y * b.w + a.z * b.x;
    r.z = a.w * b.z + a.x * b.y - a.y * b.x + a.z * b.w;
    return r;
}
__device__ __forceinline__ Q qnorm(Q a) {
    float nn = a.w * a.w + a.x * a.x + a.y * a.y + a.z * a.z;
    float inv = __frsqrt_rn(nn);
    Q r; r.w = a.w * inv; r.x = a.x * inv; r.y = a.y * inv; r.z = a.z * inv;
    return r;
}
__device__ __forceinline__ Q vquat(float vx, float vy, float vz) {
    float th = sqrtf(vx * vx + vy * vy + vz * vz);
    float s_, c_;
    __sincosf(th, &s_, &c_);
    float k = __fdividef(s_, th + EPSF);
    Q q; q.w = c_; q.x = k * vx; q.y = k * vy; q.z = k * vz;
    return q;
}

#define SEG  64
#define NSEG 32

// block: 256 thr = 64 h x 4 segments; grid (NSEG/4, H/64, B)
__global__ __launch_bounds__(256)
void seg_prod_kernel(const float* __restrict__ v, float* __restrict__ partials,
                     int S, int H) {
    const int b  = blockIdx.z;
    const int h  = blockIdx.y * 64 + (threadIdx.x & 63);
    const int sg = blockIdx.x * 4 + (threadIdx.x >> 6);
    const int s0 = sg * SEG;
    const size_t vstep = (size_t)3 * H;
    const float* vp = v + ((size_t)b * S + s0) * vstep + (size_t)h * 3;

    constexpr int CH = 8;
    float ax[CH], ay[CH], az[CH], bx[CH], by[CH], bz[CH];
#pragma unroll
    for (int i = 0; i < CH; ++i) {
        ax[i] = vp[i * vstep + 0]; ay[i] = vp[i * vstep + 1]; az[i] = vp[i * vstep + 2];
    }
    Q c = {1.f, 0.f, 0.f, 0.f};
    const int NC = SEG / CH;  // 8 chunks
    for (int cc = 0; cc < NC; cc += 2) {
        if (cc + 1 < NC) {
            const float* p = vp + (size_t)(cc + 1) * CH * vstep;
#pragma unroll
            for (int i = 0; i < CH; ++i) {
                bx[i] = p[i * vstep + 0]; by[i] = p[i * vstep + 1]; bz[i] = p[i * vstep + 2];
            }
        }
#pragma unroll
        for (int i = 0; i < CH; ++i) c = qmul(vquat(ax[i], ay[i], az[i]), c);
        if (cc + 2 < NC) {
            const float* p = vp + (size_t)(cc + 2) * CH * vstep;
#pragma unroll
            for (int i = 0; i < CH; ++i) {
                ax[i] = p[i * vstep + 0]; ay[i] = p[i * vstep + 1]; az[i] = p[i * vstep + 2];
            }
        }
#pragma unroll
        for (int i = 0; i < CH; ++i) c = qmul(vquat(bx[i], by[i], bz[i]), c);
    }
    float4* dst = (float4*)(partials + (((size_t)b * NSEG + sg) * H + h) * 4);
    *dst = make_float4(c.w, c.x, c.y, c.z);
}

// fused scan+apply: block loads all segment partials for its 64 h into LDS,
// computes exclusive prefixes locally, applies to re-derived quats, writes
// fp16 states; sg==NSEG-1 threads emit m_final.
__global__ __launch_bounds__(256)
void apply_kernel(const float* __restrict__ v, const float* __restrict__ partials,
                  unsigned short* __restrict__ st, float* __restrict__ m_final,
                  int S, int H) {
    const int b   = blockIdx.z;
    const int hb  = blockIdx.y * 64;
    const int hl  = threadIdx.x & 63;
    const int h   = hb + hl;
    const int sg  = blockIdx.x * 4 + (threadIdx.x >> 6);
    const int s0  = sg * SEG;
    const size_t vstep = (size_t)3 * H;
    const size_t sstep = (size_t)4 * H;
    const float* vp = v + ((size_t)b * S + s0) * vstep + (size_t)h * 3;
    unsigned short* sp = st + ((size_t)b * S + s0) * sstep + (size_t)h * 4;

    __shared__ float4 lp[NSEG][64];
    for (int i = threadIdx.x; i < NSEG * 64; i += 256) {
        int s2 = i >> 6, hh = i & 63;
        lp[s2][hh] = *(const float4*)(partials + (((size_t)b * NSEG + s2) * H + hb + hh) * 4);
    }
    __syncthreads();

    Q R = {1.f, 0.f, 0.f, 0.f};
    for (int s2 = 0; s2 < sg; ++s2) {           // wave-uniform trip count
        float4 pv = lp[s2][hl];
        Q pq = {pv.x, pv.y, pv.z, pv.w};
        R = qmul(pq, R);
    }

    constexpr int CH = 8;
    float ax[CH], ay[CH], az[CH], bx[CH], by[CH], bz[CH];
#pragma unroll
    for (int i = 0; i < CH; ++i) {
        ax[i] = vp[i * vstep + 0]; ay[i] = vp[i * vstep + 1]; az[i] = vp[i * vstep + 2];
    }
    const int NC = SEG / CH;
    for (int cc = 0; cc < NC; cc += 2) {
        if (cc + 1 < NC) {
            const float* pp = vp + (size_t)(cc + 1) * CH * vstep;
#pragma unroll
            for (int i = 0; i < CH; ++i) {
                bx[i] = pp[i * vstep + 0]; by[i] = pp[i * vstep + 1]; bz[i] = pp[i * vstep + 2];
            }
        }
#pragma unroll
        for (int i = 0; i < CH; ++i) {
            R = qmul(vquat(ax[i], ay[i], az[i]), R);
            Q m = qnorm(R);
            ushort4 u; u.x = f2h(m.w); u.y = f2h(m.x); u.z = f2h(m.y); u.w = f2h(m.z);
            *(ushort4*)(sp + (size_t)(cc * CH + i) * sstep) = u;
        }
        if (cc + 2 < NC) {
            const float* pp = vp + (size_t)(cc + 2) * CH * vstep;
#pragma unroll
            for (int i = 0; i < CH; ++i) {
                ax[i] = pp[i * vstep + 0]; ay[i] = pp[i * vstep + 1]; az[i] = pp[i * vstep + 2];
            }
        }
#pragma unroll
        for (int i = 0; i < CH; ++i) {
            R = qmul(vquat(bx[i], by[i], bz[i]), R);
            Q m = qnorm(R);
            ushort4 u; u.x = f2h(m.w); u.y = f2h(m.x); u.z = f2h(m.y); u.w = f2h(m.z);
            *(ushort4*)(sp + (size_t)((cc + 1) * CH + i) * sstep) = u;
        }
    }

    if (sg == NSEG - 1) {
        Q m = qnorm(R);     // inclusive product of whole chain
        float* mf = m_final + ((size_t)b * H + h) * 4;
        mf[0] = m.w; mf[1] = m.x; mf[2] = m.y; mf[3] = m.z;
    }
}

// ---------------- launch ----------------

extern "C" void kernel_launch(void* const* d_in, const int* in_sizes, int n_in,
                              void* d_out, int out_size, void* d_ws, size_t ws_size,
                              hipStream_t stream) {
    const float* x     = (const float*)d_in[0];
    const float* W_in  = (const float*)d_in[1];
    const float* b_in  = (const float*)d_in[2];
    const float* W_out = (const float*)d_in[3];
    const float* b_out = (const float*)d_in[4];
    float* out = (float*)d_out;

    const int B = 4, S = 2048, D = 1024, H = 1024;
    const int M  = B * S;    // 8192
    const int N1 = 3 * H;    // 3072
    const int K1 = D;        // 1024
    const int N2 = D;        // 1024
    const int K2 = 4 * H;    // 4096

    char* ws = (char*)d_ws;
    float*          v    = (float*)(ws);                        // 96 MB
    unsigned short* st   = (unsigned short*)(ws + 100663296u);  // 64 MB (after GEMM1)
    unsigned short* x16  = (unsigned short*)(ws + 100663296u);  // consumed by GEMM1
    unsigned short* wi16 = (unsigned short*)(ws + 100663296u + 16777216u);
    unsigned short* wo16 = (unsigned short*)(ws + 167772160u);  // 8 MB, lives to GEMM2

    // partials (2 MB) live in d_out — free until GEMM2 overwrites it last.
    float* partials = out;

    const int nx  = M * K1;    // 8388608
    const int nw  = N1 * K1;   // 3145728
    const int nwo = N2 * K2;   // 4194304
    const int n4  = (nx + nw + nwo) / 4;

    prep_kernel<<<(n4 + 255) / 256, 256, 0, stream>>>(
        (const float4*)x, (ushort4*)x16, (const float4*)W_in, (ushort4*)wi16,
        (const float4*)W_out, (ushort4*)wo16, nx / 4, nw / 4, nwo / 4);

    // v = x @ W_in^T + b_in   (fp16, 128x128 BK=64 swizzled, 32x32x16 MFMA)
    gemm_bt<128, 128, 64><<<dim3(N1 / 128, M / 128), 256, 32768, stream>>>(
        x16, wi16, b_in, v, M, N1, K1);

    // hierarchical scan (scan fused into apply)
    dim3 sg_grid(NSEG / 4, H / 64, B);
    seg_prod_kernel<<<sg_grid, 256, 0, stream>>>(v, partials, S, H);
    apply_kernel<<<sg_grid, 256, 0, stream>>>(v, partials, st, out + (size_t)M * D, S, H);

    // out = states @ W_out^T + b_out  (fp16, 128x128 BK=64 swizzled, 32x32x16)
    gemm_bt<128, 128, 64><<<dim3(N2 / 128, M / 128), 256, 32768, stream>>>(
        st, wo16, b_out, out, M, N2, K2);
}

// Round 11
// 313.288 us; speedup vs baseline: 1.1153x; 1.0378x over previous
//
#include <hip/hip_runtime.h>
#include <hip/hip_bf16.h>
#include <stdint.h>

#define EPSF 1e-8f

typedef __attribute__((ext_vector_type(8))) short short8;
typedef __attribute__((ext_vector_type(8))) _Float16 half8;
typedef __attribute__((ext_vector_type(16))) float floatx16;

__device__ __forceinline__ unsigned short f2h(float f) {
    _Float16 h = (_Float16)f;
    return __builtin_bit_cast(unsigned short, h);
}
__device__ __forceinline__ float h2f(unsigned short u) {
    return (float)__builtin_bit_cast(_Float16, u);
}

// ---------------- fused conversion kernel (float4-vectorized) ----------------

__global__ void prep_kernel(const float4* __restrict__ x4, ushort4* __restrict__ x16,
                            const float4* __restrict__ wi4, ushort4* __restrict__ wi16,
                            const float4* __restrict__ wo4, ushort4* __restrict__ wo16,
                            int nx4, int nw4, int nwo4) {
    int i = blockIdx.x * blockDim.x + threadIdx.x;
    float4 f; ushort4 u;
    if (i < nx4) {
        f = x4[i];
        u.x = f2h(f.x); u.y = f2h(f.y); u.z = f2h(f.z); u.w = f2h(f.w);
        x16[i] = u;
    } else if (i < nx4 + nw4) {
        int j = i - nx4;
        f = wi4[j];
        u.x = f2h(f.x); u.y = f2h(f.y); u.z = f2h(f.z); u.w = f2h(f.w);
        wi16[j] = u;
    } else if (i < nx4 + nw4 + nwo4) {
        int j = i - nx4 - nw4;
        f = wo4[j];
        u.x = f2h(f.x); u.y = f2h(f.y); u.z = f2h(f.z); u.w = f2h(f.w);
        wo16[j] = u;
    }
}

// ---------------- MFMA GEMM (C = A * B^T + bias), fp16, 32x32x16 ----------------
// XOR-swizzled LDS staging. 32x32x16 MFMA (r10: VALUBusy 38->13%).
// Fragment layouts:
//   A/B: m|n = lane&31, k = (lane>>5)*8 + i   (4 VGPRs = 8 fp16)
//   C/D: col = lane&31, row = (reg&3) + 8*(reg>>2) + 4*(lane>>5)  [m74/m101]
// HALFOUT: write C as fp16 bits (for v); else fp32.

__device__ __forceinline__ void gld16(const unsigned short* g, unsigned short* l) {
    __builtin_amdgcn_global_load_lds(
        (const __attribute__((address_space(1))) unsigned int*)g,
        (__attribute__((address_space(3))) unsigned int*)l, 16, 0, 0);
}

template <int BM, int BN, int BK, bool HALFOUT>
__global__ __launch_bounds__(256)
void gemm_bt(const unsigned short* __restrict__ Am, const unsigned short* __restrict__ Bm,
             const float* __restrict__ bias, void* __restrict__ Cv,
             int M, int N, int K) {
    constexpr int IF  = BM / 64;       // 32-row fragments per wave (waves 2x2)
    constexpr int JF  = BN / 64;       // 32-col fragments per wave
    constexpr int KH  = BK / 16;       // mfma k-steps per tile
    constexpr int CPR = BK / 8;        // 16B chunks per row
    extern __shared__ unsigned short smem[];
    unsigned short* sA = smem;
    unsigned short* sB = smem + BM * BK;

    const int tid  = threadIdx.x;
    const int lane = tid & 63;
    const int wid  = tid >> 6;
    const int wr   = wid >> 1, wc = wid & 1;
    const int m32  = lane & 31, half = lane >> 5;

    const int rowA0 = blockIdx.y * BM;
    const int rowB0 = blockIdx.x * BN;

    floatx16 acc[IF][JF];
#pragma unroll
    for (int i = 0; i < IF; i++)
#pragma unroll
        for (int j = 0; j < JF; j++)
#pragma unroll
            for (int r = 0; r < 16; r++) acc[i][j][r] = 0.f;

    const int nk = K / BK;
    for (int kt = 0; kt < nk; ++kt) {
        const int k0 = kt * BK;
#pragma unroll
        for (int i = 0; i < BM * CPR / 256; i++) {
            int c = tid + 256 * i;
            int r = c / CPR, ccl = c % CPR;
            int ccg = ccl ^ (r & (CPR - 1));   // swizzled source chunk
            gld16(Am + (size_t)(rowA0 + r) * K + k0 + ccg * 8, sA + c * 8);
        }
#pragma unroll
        for (int i = 0; i < BN * CPR / 256; i++) {
            int c = tid + 256 * i;
            int r = c / CPR, ccl = c % CPR;
            int ccg = ccl ^ (r & (CPR - 1));
            gld16(Bm + (size_t)(rowB0 + r) * K + k0 + ccg * 8, sB + c * 8);
        }
        __syncthreads();

#pragma unroll
        for (int kh = 0; kh < KH; kh++) {
            const int kc = kh * 2 + half;      // 16B chunk index of this lane's k
            short8 a[IF], b[JF];
#pragma unroll
            for (int i = 0; i < IF; i++) {
                int ra = wr * (BM / 2) + i * 32 + m32;
                int pa = ra * CPR + (kc ^ (ra & (CPR - 1)));
                a[i] = *(const short8*)(sA + pa * 8);
            }
#pragma unroll
            for (int j = 0; j < JF; j++) {
                int rb = wc * (BN / 2) + j * 32 + m32;
                int pb = rb * CPR + (kc ^ (rb & (CPR - 1)));
                b[j] = *(const short8*)(sB + pb * 8);
            }
#pragma unroll
            for (int i = 0; i < IF; i++)
#pragma unroll
                for (int j = 0; j < JF; j++)
                    acc[i][j] = __builtin_amdgcn_mfma_f32_32x32x16_f16(
                        __builtin_bit_cast(half8, a[i]), __builtin_bit_cast(half8, b[j]),
                        acc[i][j], 0, 0, 0);
        }
        __syncthreads();
    }

    // C/D: col=lane&31, row=(reg&3)+8*(reg>>2)+4*half  [verified m74/m101]
#pragma unroll
    for (int i = 0; i < IF; i++) {
#pragma unroll
        for (int j = 0; j < JF; j++) {
            int col  = rowB0 + wc * (BN / 2) + j * 32 + m32;
            float bv = bias[col];
#pragma unroll
            for (int r = 0; r < 16; r++) {
                int row = rowA0 + wr * (BM / 2) + i * 32 + (r & 3) + 8 * (r >> 2) + 4 * half;
                if (HALFOUT)
                    ((unsigned short*)Cv)[(size_t)row * N + col] = f2h(acc[i][j][r] + bv);
                else
                    ((float*)Cv)[(size_t)row * N + col] = acc[i][j][r] + bv;
            }
        }
    }
}

// ---------------- hierarchical quaternion prefix-product scan ----------------
// v is stored as fp16 bits (halves GEMM1 write + scan read traffic).

struct Q { float w, x, y, z; };

__device__ __forceinline__ Q qmul(Q a, Q b) {   // a later (left), b earlier
    Q r;
    r.w = a.w * b.w - a.x * b.x - a.y * b.y - a.z * b.z;
    r.x = a.w * b.x + a.x * b.w + a.y * b.z - a.z * b.y;
    r.y = a.w * b.y - a.x * b.z + a.y * b.w + a.z * b.x;
    r.z = a.w * b.z + a.x * b.y - a.y * b.x + a.z * b.w;
    return r;
}
__device__ __forceinline__ Q qnorm(Q a) {
    float nn = a.w * a.w + a.x * a.x + a.y * a.y + a.z * a.z;
    float inv = __frsqrt_rn(nn);
    Q r; r.w = a.w * inv; r.x = a.x * inv; r.y = a.y * inv; r.z = a.z * inv;
    return r;
}
__device__ __forceinline__ Q vquat(float vx, float vy, float vz) {
    float th = sqrtf(vx * vx + vy * vy + vz * vz);
    float s_, c_;
    __sincosf(th, &s_, &c_);
    float k = __fdividef(s_, th + EPSF);
    Q q; q.w = c_; q.x = k * vx; q.y = k * vy; q.z = k * vz;
    return q;
}

#define SEG  64
#define NSEG 32

// block: 256 thr = 64 h x 4 segments; grid (NSEG/4, H/64, B)
__global__ __launch_bounds__(256)
void seg_prod_kernel(const unsigned short* __restrict__ v, float* __restrict__ partials,
                     int S, int H) {
    const int b  = blockIdx.z;
    const int h  = blockIdx.y * 64 + (threadIdx.x & 63);
    const int sg = blockIdx.x * 4 + (threadIdx.x >> 6);
    const int s0 = sg * SEG;
    const size_t vstep = (size_t)3 * H;
    const unsigned short* vp = v + ((size_t)b * S + s0) * vstep + (size_t)h * 3;

    constexpr int CH = 8;
    float ax[CH], ay[CH], az[CH], bx[CH], by[CH], bz[CH];
#pragma unroll
    for (int i = 0; i < CH; ++i) {
        ax[i] = h2f(vp[i * vstep + 0]); ay[i] = h2f(vp[i * vstep + 1]); az[i] = h2f(vp[i * vstep + 2]);
    }
    Q c = {1.f, 0.f, 0.f, 0.f};
    const int NC = SEG / CH;  // 8 chunks
    for (int cc = 0; cc < NC; cc += 2) {
        if (cc + 1 < NC) {
            const unsigned short* p = vp + (size_t)(cc + 1) * CH * vstep;
#pragma unroll
            for (int i = 0; i < CH; ++i) {
                bx[i] = h2f(p[i * vstep + 0]); by[i] = h2f(p[i * vstep + 1]); bz[i] = h2f(p[i * vstep + 2]);
            }
        }
#pragma unroll
        for (int i = 0; i < CH; ++i) c = qmul(vquat(ax[i], ay[i], az[i]), c);
        if (cc + 2 < NC) {
            const unsigned short* p = vp + (size_t)(cc + 2) * CH * vstep;
#pragma unroll
            for (int i = 0; i < CH; ++i) {
                ax[i] = h2f(p[i * vstep + 0]); ay[i] = h2f(p[i * vstep + 1]); az[i] = h2f(p[i * vstep + 2]);
            }
        }
#pragma unroll
        for (int i = 0; i < CH; ++i) c = qmul(vquat(bx[i], by[i], bz[i]), c);
    }
    float4* dst = (float4*)(partials + (((size_t)b * NSEG + sg) * H + h) * 4);
    *dst = make_float4(c.w, c.x, c.y, c.z);
}

// fused scan+apply: block loads all segment partials for its 64 h into LDS,
// computes exclusive prefixes locally, applies to re-derived quats, writes
// fp16 states; sg==NSEG-1 threads emit m_final.
__global__ __launch_bounds__(256)
void apply_kernel(const unsigned short* __restrict__ v, const float* __restrict__ partials,
                  unsigned short* __restrict__ st, float* __restrict__ m_final,
                  int S, int H) {
    const int b   = blockIdx.z;
    const int hb  = blockIdx.y * 64;
    const int hl  = threadIdx.x & 63;
    const int h   = hb + hl;
    const int sg  = blockIdx.x * 4 + (threadIdx.x >> 6);
    const int s0  = sg * SEG;
    const size_t vstep = (size_t)3 * H;
    const size_t sstep = (size_t)4 * H;
    const unsigned short* vp = v + ((size_t)b * S + s0) * vstep + (size_t)h * 3;
    unsigned short* sp = st + ((size_t)b * S + s0) * sstep + (size_t)h * 4;

    __shared__ float4 lp[NSEG][64];
    for (int i = threadIdx.x; i < NSEG * 64; i += 256) {
        int s2 = i >> 6, hh = i & 63;
        lp[s2][hh] = *(const float4*)(partials + (((size_t)b * NSEG + s2) * H + hb + hh) * 4);
    }
    __syncthreads();

    Q R = {1.f, 0.f, 0.f, 0.f};
    for (int s2 = 0; s2 < sg; ++s2) {           // wave-uniform trip count
        float4 pv = lp[s2][hl];
        Q pq = {pv.x, pv.y, pv.z, pv.w};
        R = qmul(pq, R);
    }

    constexpr int CH = 8;
    float ax[CH], ay[CH], az[CH], bx[CH], by[CH], bz[CH];
#pragma unroll
    for (int i = 0; i < CH; ++i) {
        ax[i] = h2f(vp[i * vstep + 0]); ay[i] = h2f(vp[i * vstep + 1]); az[i] = h2f(vp[i * vstep + 2]);
    }
    const int NC = SEG / CH;
    for (int cc = 0; cc < NC; cc += 2) {
        if (cc + 1 < NC) {
            const unsigned short* pp = vp + (size_t)(cc + 1) * CH * vstep;
#pragma unroll
            for (int i = 0; i < CH; ++i) {
                bx[i] = h2f(pp[i * vstep + 0]); by[i] = h2f(pp[i * vstep + 1]); bz[i] = h2f(pp[i * vstep + 2]);
            }
        }
#pragma unroll
        for (int i = 0; i < CH; ++i) {
            R = qmul(vquat(ax[i], ay[i], az[i]), R);
            Q m = qnorm(R);
            ushort4 u; u.x = f2h(m.w); u.y = f2h(m.x); u.z = f2h(m.y); u.w = f2h(m.z);
            *(ushort4*)(sp + (size_t)(cc * CH + i) * sstep) = u;
        }
        if (cc + 2 < NC) {
            const unsigned short* pp = vp + (size_t)(cc + 2) * CH * vstep;
#pragma unroll
            for (int i = 0; i < CH; ++i) {
                ax[i] = h2f(pp[i * vstep + 0]); ay[i] = h2f(pp[i * vstep + 1]); az[i] = h2f(pp[i * vstep + 2]);
            }
        }
#pragma unroll
        for (int i = 0; i < CH; ++i) {
            R = qmul(vquat(bx[i], by[i], bz[i]), R);
            Q m = qnorm(R);
            ushort4 u; u.x = f2h(m.w); u.y = f2h(m.x); u.z = f2h(m.y); u.w = f2h(m.z);
            *(ushort4*)(sp + (size_t)((cc + 1) * CH + i) * sstep) = u;
        }
    }

    if (sg == NSEG - 1) {
        Q m = qnorm(R);     // inclusive product of whole chain
        float* mf = m_final + ((size_t)b * H + h) * 4;
        mf[0] = m.w; mf[1] = m.x; mf[2] = m.y; mf[3] = m.z;
    }
}

// ---------------- launch ----------------

extern "C" void kernel_launch(void* const* d_in, const int* in_sizes, int n_in,
                              void* d_out, int out_size, void* d_ws, size_t ws_size,
                              hipStream_t stream) {
    const float* x     = (const float*)d_in[0];
    const float* W_in  = (const float*)d_in[1];
    const float* b_in  = (const float*)d_in[2];
    const float* W_out = (const float*)d_in[3];
    const float* b_out = (const float*)d_in[4];
    float* out = (float*)d_out;

    const int B = 4, S = 2048, D = 1024, H = 1024;
    const int M  = B * S;    // 8192
    const int N1 = 3 * H;    // 3072
    const int K1 = D;        // 1024
    const int N2 = D;        // 1024
    const int K2 = 4 * H;    // 4096

    // ws layout (bytes):
    //   [0, 50331648)                    v     fp16 M*N1 (48 MB)
    //   [50331648, 117440512)            st    fp16 M*K2 (64 MB); x16/wi16
    //                                    overlap here (consumed by GEMM1)
    //   [117440512, 125829120)           wo16  fp16 N2*K2 (8 MB)
    char* ws = (char*)d_ws;
    unsigned short* v    = (unsigned short*)(ws);
    unsigned short* st   = (unsigned short*)(ws + 50331648u);
    unsigned short* x16  = (unsigned short*)(ws + 50331648u);
    unsigned short* wi16 = (unsigned short*)(ws + 50331648u + 16777216u);
    unsigned short* wo16 = (unsigned short*)(ws + 117440512u);

    // partials (2 MB) live in d_out — free until GEMM2 overwrites it last.
    float* partials = out;

    const int nx  = M * K1;    // 8388608
    const int nw  = N1 * K1;   // 3145728
    const int nwo = N2 * K2;   // 4194304
    const int n4  = (nx + nw + nwo) / 4;

    prep_kernel<<<(n4 + 255) / 256, 256, 0, stream>>>(
        (const float4*)x, (ushort4*)x16, (const float4*)W_in, (ushort4*)wi16,
        (const float4*)W_out, (ushort4*)wo16, nx / 4, nw / 4, nwo / 4);

    // v = x @ W_in^T + b_in   (fp16 out; 128x128 BK=64 swizzled, 32x32x16)
    gemm_bt<128, 128, 64, true><<<dim3(N1 / 128, M / 128), 256, 32768, stream>>>(
        x16, wi16, b_in, v, M, N1, K1);

    // hierarchical scan (scan fused into apply)
    dim3 sg_grid(NSEG / 4, H / 64, B);
    seg_prod_kernel<<<sg_grid, 256, 0, stream>>>(v, partials, S, H);
    apply_kernel<<<sg_grid, 256, 0, stream>>>(v, partials, st, out + (size_t)M * D, S, H);

    // out = states @ W_out^T + b_out  (fp32 out; BK=128: half the barrier
    // drains — GEMM2 is grid-capped at 2 blocks/CU so no occupancy loss)
    gemm_bt<128, 128, 128, false><<<dim3(N2 / 128, M / 128), 256, 65536, stream>>>(
        st, wo16, b_out, out, M, N2, K2);
}